// Round 11
// baseline (99.744 us; speedup 1.0000x reference)
//
#include <hip/hip_runtime.h>

// HebbianNet: 3x (GEMV-ish layer + linearized hebbian shift). ALL FP32.
// conv1(1x1,3->MH) -> conv2(1x1,MH->1) with no nonlinearity is a single
// affine map of (vi, w, vj):
//   shift = r*(a0*vi + a1*W + a2*vj + cc),  a_c = sum_h cw2[h]*cw1[h][c],
//   cc = sum_h cw2[h]*cb1[h] + cb2,         r = RATE/batch_num
// => out[b,o] = vj + r*(a0*Sum_i v^2 + a1*dot[b,o] + (a2*vj + cc)*Sum_i v)
// with dot = v@W^T (pre-bias), vj = relu(dot + bias).
//
// Round-11: RAMP HALVING. Rounds 9/10 proved barrier-arrival contention is
// a non-term (flat->tree null). The one lever with a measured slope left is
// workgroup dispatch ramp (256->128 blocks gained 4us => ~31ns/WG). Now:
// 64 blocks x 1024 threads (16 waves; wave w = row o12 = blk*16+w for
// layers 1/2; waves 0-7 own layer-3 rows). LDS 128KB (vsh 32 + W2 64 +
// W3 32) -> still 1 block/CU by capacity, 64 <= 256 CUs co-resident.
// Halves WG dispatches and barrier arrivals; per-phase LDS-dot compute
// doubles (cheap part). Everything else byte-identical to round 10:
// pure-relaxed reset-free tree barrier (PER_LEAF 16->8), zero wbl2/inv,
// sc0|sc1 agent ops through IF for cross-phase bytes, W2/W3 DMA-staged to
// LDS at t=0 behind a sched_barrier pin, lgkm-only phase-1 barriers.
// Kernel ladder: 73 -> 41.5 -> ~25 -> ~21 -> (this) ~19us predicted.

#define RATE_F 0.001f
#define AS1 __attribute__((address_space(1)))
#define AS3 __attribute__((address_space(3)))

#define NBLK 64
#define TPB  1024
#define NLEAF 8
#define PER_LEAF (NBLK / NLEAF)          // 8 arrivals per leaf per launch

// Barrier counters in module .data: zeroed at load, never re-poisoned.
// Each counter on its own 128B cacheline. [barrier][leaf]
__device__ unsigned g_leaf[2][NLEAF][32] = {};
__device__ unsigned g_root[2][32] = {};

__device__ __forceinline__ void gl_lds16(const float* g, float* l)
{
    // one instruction: 64 lanes x 16B -> LDS[l .. l+1024), l wave-uniform
    __builtin_amdgcn_global_load_lds((const AS1 void*)g, (AS3 void*)l, 16, 0, 0);
}

// Raw workgroup barrier: waits LDS/SMEM (lgkmcnt) only, NOT vmcnt -- keeps
// the W2/W3 DMA in flight across phase-1 syncs.
__device__ __forceinline__ void lgkm_barrier()
{
    asm volatile("s_waitcnt lgkmcnt(0)" ::: "memory");
    __builtin_amdgcn_s_barrier();
    __builtin_amdgcn_sched_barrier(0);
}

// coherent staging (phases 2/3): agent-scope loads bypass stale L1/L2,
// fetch from IF (the coherence point). 8B granules: 4 issues/thread.
__device__ __forceinline__ void stage_v_coh(const float* __restrict__ vin,
                                            float* __restrict__ vsh, int tid)
{
    const unsigned long long* p = (const unsigned long long*)vin; // 4096 qwords
    unsigned long long* q = (unsigned long long*)vsh;
    #pragma unroll
    for (int k = 0; k < 4; k++) {
        const int i = tid + k * TPB;            // wave-coalesced qwords
        q[i] = __hip_atomic_load(p + i, __ATOMIC_RELAXED,
                                 __HIP_MEMORY_SCOPE_AGENT);
    }
}

// waves 0-7 only: wave b reduces batch b (64 lanes x 4 float4 = 1024 f32).
// Waves 8-15 fall through to the barrier.
__device__ __forceinline__ void batch_sums(const float* __restrict__ vsh,
                                           float* __restrict__ svs,
                                           float* __restrict__ s2s,
                                           int w, int lane)
{
    if (w < 8) {
        const int b = w, j = lane;
        float sv = 0.f, s2 = 0.f;
        #pragma unroll
        for (int k = 0; k < 4; k++) {
            const float4 v = *(const float4*)&vsh[b * 1024 + (j + k * 64) * 4];
            sv += v.x + v.y + v.z + v.w;
            s2 += v.x * v.x + v.y * v.y + v.z * v.z + v.w * v.w;
        }
        #pragma unroll
        for (int m = 32; m >= 1; m >>= 1) {     // full 64-lane butterfly
            sv += __shfl_xor(sv, m, 64);
            s2 += __shfl_xor(s2, m, 64);
        }
        if (j == 0) { svs[b] = sv; s2s[b] = s2; }
    }
}

__device__ __forceinline__ void epilogue(
    float acc[8], float bias_o, const float* __restrict__ svs,
    const float* __restrict__ s2s,
    float a0, float a1, float a2, float cc, float rr,
    float* __restrict__ vout, int o, int n_out, int lane, bool coh_store)
{
    #pragma unroll
    for (int b = 0; b < 8; b++) {
        #pragma unroll
        for (int m = 32; m >= 1; m >>= 1)
            acc[b] += __shfl_xor(acc[b], m, 64);
    }
    if (lane < 8) {
        const int b = lane;
        const float dot = acc[b];
        float vj = dot + bias_o;
        vj = vj > 0.f ? vj : 0.f;
        const float outv = vj + rr * (a0 * s2s[b] + a1 * dot
                                      + (a2 * vj + cc) * svs[b]);
        float* dst = vout + (size_t)b * n_out + o;
        if (coh_store)
            __hip_atomic_store(dst, outv, __ATOMIC_RELAXED,
                               __HIP_MEMORY_SCOPE_AGENT);
        else
            *dst = outv;
    }
}

__device__ __forceinline__ void layer_reg(
    const float4 wr[4], float bias_o, const float* __restrict__ vsh,
    const float* __restrict__ svs, const float* __restrict__ s2s,
    float a0, float a1, float a2, float cc, float rr,
    float* __restrict__ vout, int o, int n_out, int lane, bool coh_store)
{
    float acc[8] = {0.f, 0.f, 0.f, 0.f, 0.f, 0.f, 0.f, 0.f};
    #pragma unroll
    for (int u = 0; u < 4; u++) {
        const float4 wv = wr[u];
        #pragma unroll
        for (int b = 0; b < 8; b++) {
            const float4 v = *(const float4*)&vsh[b * 1024 + (u * 64 + lane) * 4];
            acc[b] += wv.x * v.x + wv.y * v.y + wv.z * v.z + wv.w * v.w;
        }
    }
    epilogue(acc, bias_o, svs, s2s, a0, a1, a2, cc, rr,
             vout, o, n_out, lane, coh_store);
}

__device__ __forceinline__ void layer_lds(
    const float* __restrict__ wlds, float bias_o, const float* __restrict__ vsh,
    const float* __restrict__ svs, const float* __restrict__ s2s,
    float a0, float a1, float a2, float cc, float rr,
    float* __restrict__ vout, int o, int n_out, int lane, bool coh_store)
{
    float acc[8] = {0.f, 0.f, 0.f, 0.f, 0.f, 0.f, 0.f, 0.f};
    #pragma unroll
    for (int u = 0; u < 4; u++) {
        const float4 wv = *(const float4*)&wlds[(u * 64 + lane) * 4];
        #pragma unroll
        for (int b = 0; b < 8; b++) {
            const float4 v = *(const float4*)&vsh[b * 1024 + (u * 64 + lane) * 4];
            acc[b] += wv.x * v.x + wv.y * v.y + wv.z * v.z + wv.w * v.w;
        }
    }
    epilogue(acc, bias_o, svs, s2s, a0, a1, a2, cc, rr,
             vout, o, n_out, lane, coh_store);
}

// Reset-free pure-relaxed TREE barrier (no wbl2/inv, no initialization).
// Leaf = blk&7: 8 arrivals/launch/leaf; 8th arriver adds 1 to root;
// spinners poll root (8 adds/launch). Launch index n = t/PER_LEAF; wait
// for root >= (n+1)*NLEAF, wrap-safe. Launches stream-serialize, so
// tickets of one launch span exactly [n*PER_LEAF,(n+1)*PER_LEAF) per leaf.
// Leading __syncthreads supplies the vmcnt(0) drain that orders this
// block's agent-scope v-stores (and the weight DMA) before arrival.
__device__ __forceinline__ void grid_bar(unsigned* leaf, unsigned* root)
{
    __syncthreads();   // s_waitcnt vmcnt(0): block's sc0|sc1 stores COMPLETE
    if (threadIdx.x == 0) {
        const unsigned t =
            __hip_atomic_fetch_add(leaf, 1u, __ATOMIC_RELAXED,
                                   __HIP_MEMORY_SCOPE_AGENT);
        const unsigned n = t / PER_LEAF;               // launch index
        if ((t & (PER_LEAF - 1u)) == PER_LEAF - 1u)    // last on this leaf
            __hip_atomic_fetch_add(root, 1u, __ATOMIC_RELAXED,
                                   __HIP_MEMORY_SCOPE_AGENT);
        const unsigned target = (n + 1u) * NLEAF;
        while ((int)(__hip_atomic_load(root, __ATOMIC_RELAXED,
                                       __HIP_MEMORY_SCOPE_AGENT) - target) < 0)
            __builtin_amdgcn_s_sleep(1);
    }
    __syncthreads();
}

__global__ __launch_bounds__(TPB) void hebb_fused(
    const float* __restrict__ x,
    const float* __restrict__ W1, const float* __restrict__ b1,
    const float* __restrict__ W2, const float* __restrict__ b2,
    const float* __restrict__ W3, const float* __restrict__ b3,
    const float* __restrict__ cw1, const float* __restrict__ cb1,
    const float* __restrict__ cw2, const float* __restrict__ cb2,
    const int* __restrict__ batch_num,
    float* __restrict__ v1, float* __restrict__ v2, float* __restrict__ out)
{
    __shared__ __align__(16) float vsh[8 * 1024];    // 32 KB activations
    __shared__ __align__(16) float w2sh[16 * 1024];  // 64 KB: W2 rows, 1/wave
    __shared__ __align__(16) float w3sh[8 * 1024];   // 32 KB: W3 rows (w 8-15)
    __shared__ float svs[8], s2s[8];

    const int tid  = threadIdx.x;
    const int w    = tid >> 6, lane = tid & 63;
    const int blk  = blockIdx.x;
    const int leaf = blk & (NLEAF - 1);
    const int o12  = blk * 16 + w;           // layer 1/2 row (0..1023)
    const int o3   = blk * 8 + (w & 7);      // layer 3 row (0..511)
    const bool act3 = (w < 8);

    // ---- (1) x -> regs (oldest vmem ops: counted waits see only these) ----
    float4 xr[2];
    {
        const float4* xp = (const float4*)x;
        #pragma unroll
        for (int k = 0; k < 2; k++) xr[k] = xp[tid + k * TPB];
    }
    // ---- (2) W1 row -> regs ----
    float4 w1r[4];
    {
        const float4* r1 = (const float4*)(W1 + (size_t)o12 * 1024);
        #pragma unroll
        for (int u = 0; u < 4; u++) w1r[u] = r1[u * 64 + lane];
    }
    // ---- (3) biases ----
    const float bias1 = b1[o12];
    const float bias2 = b2[o12];
    const float bias3 = act3 ? b3[o3] : 0.f;
    // ---- (4) coefficients: wave-uniform, per-thread from SMEM ----
    float a0 = 0.f, a1 = 0.f, a2 = 0.f, cc = 0.f;
    #pragma unroll
    for (int h = 0; h < 8; h++) {
        const float w2c = cw2[h];
        a0 += w2c * cw1[h * 3 + 0];
        a1 += w2c * cw1[h * 3 + 1];
        a2 += w2c * cw1[h * 3 + 2];
        cc += w2c * cb1[h];
    }
    cc += cb2[0];
    const float rr = RATE_F / (float)batch_num[0];

    // pin: everything above ISSUES before the DMA below
    __builtin_amdgcn_sched_barrier(0);

    // ---- (5) DMA-stage W2/W3 rows into LDS; stays in flight through all
    // phase-1 lgkm-only barriers, drained first at grid_bar ----
    {
        const float* g2 = W2 + (size_t)o12 * 1024 + lane * 4;
        float* l2 = w2sh + w * 1024;                 // wave-uniform dest
        #pragma unroll
        for (int c = 0; c < 4; c++) gl_lds16(g2 + c * 256, l2 + c * 256);
        if (w >= 8) {                                // waves 8..15: W3 rows
            const int rdx = w - 8;
            const float* g3 = W3 + (size_t)(blk * 8 + rdx) * 1024 + lane * 4;
            float* l3 = w3sh + rdx * 1024;
            #pragma unroll
            for (int c = 0; c < 4; c++) gl_lds16(g3 + c * 256, l3 + c * 256);
        }
    }

    // ---- (6) x -> LDS (counted vmcnt wait covers only xr) ----
    {
        float4* q = (float4*)vsh;
        #pragma unroll
        for (int k = 0; k < 2; k++) q[tid + k * TPB] = xr[k];
    }

    lgkm_barrier();                      // LDS visibility only; DMA untouched
    batch_sums(vsh, svs, s2s, w, lane);
    lgkm_barrier();
    layer_reg(w1r, bias1, vsh, svs, s2s, a0, a1, a2, cc, rr,
              v1, o12, 1024, lane, true);

    grid_bar(&g_leaf[0][leaf][0], &g_root[0][0]);

    stage_v_coh(v1, vsh, tid);
    __syncthreads();
    batch_sums(vsh, svs, s2s, w, lane);
    __syncthreads();
    layer_lds(w2sh + w * 1024, bias2, vsh, svs, s2s, a0, a1, a2, cc, rr,
              v2, o12, 1024, lane, true);

    grid_bar(&g_leaf[1][leaf][0], &g_root[1][0]);

    stage_v_coh(v2, vsh, tid);
    __syncthreads();
    batch_sums(vsh, svs, s2s, w, lane);
    __syncthreads();
    if (act3)
        layer_lds(w3sh + (w & 7) * 1024, bias3, vsh, svs, s2s,
                  a0, a1, a2, cc, rr, out, o3, 512, lane, false);
}

extern "C" void kernel_launch(void* const* d_in, const int* in_sizes, int n_in,
                              void* d_out, int out_size, void* d_ws, size_t ws_size,
                              hipStream_t stream) {
    const float* x   = (const float*)d_in[0];
    const float* W1  = (const float*)d_in[1];
    const float* b1  = (const float*)d_in[2];
    const float* W2  = (const float*)d_in[3];
    const float* b2  = (const float*)d_in[4];
    const float* W3  = (const float*)d_in[5];
    const float* b3  = (const float*)d_in[6];
    const float* cw1 = (const float*)d_in[7];
    const float* cb1 = (const float*)d_in[8];
    const float* cw2 = (const float*)d_in[9];
    const float* cb2 = (const float*)d_in[10];
    const int*   bn  = (const int*)d_in[11];

    float* v1  = (float*)d_ws;            // 8x1024 fp32 intermediate
    float* v2  = v1 + 8 * 1024;           // 8x1024 fp32 intermediate
    float* out = (float*)d_out;

    hebb_fused<<<NBLK, TPB, 0, stream>>>(x, W1, b1, W2, b2, W3, b3,
                                         cw1, cb1, cw2, cb2, bn,
                                         v1, v2, out);
}

// Round 12
// 96.853 us; speedup vs baseline: 1.0298x; 1.0298x over previous
//
#include <hip/hip_runtime.h>

// HebbianNet: 3x (GEMV-ish layer + linearized hebbian shift). ALL FP32.
// conv1(1x1,3->MH) -> conv2(1x1,MH->1) with no nonlinearity is a single
// affine map of (vi, w, vj):
//   shift = r*(a0*vi + a1*W + a2*vj + cc),  a_c = sum_h cw2[h]*cw1[h][c],
//   cc = sum_h cw2[h]*cb1[h] + cb2,         r = RATE/batch_num
// => out[b,o] = vj + r*(a0*Sum_i v^2 + a1*dot[b,o] + (a2*vj + cc)*Sum_i v)
// with dot = v@W^T (pre-bias), vj = relu(dot + bias).
//
// Round-12: REVERT TO BEST (round-10, 97.5us e2e). Round-11's 64x1024
// reshape regressed (+2.2us): halving ramp was outweighed by doubling
// per-CU phase work with no co-resident block to overlap it. Experiment
// ladder 166 -> 149.5 -> 119.6 -> 103.6 -> 99.8 -> 97.9 -> 97.5 -> 99.7(reg)
// => controllable floor reached. Kernel does ~6us intrinsic work in ~21us;
// the timed iteration is dominated by harness-fixed terms (268MB workspace
// re-poison fill ~40us @83% HBM peak + ~36us launch machinery).
// Configuration: 128 blocks x 512 threads, 1 block/CU by LDS capacity;
// reset-free pure-relaxed TREE barrier (8 leaves + root, ticket protocol,
// zero initialization, zero wbl2/inv instructions anywhere); sc0|sc1
// agent-scope ops through IF for all cross-phase bytes (ordering structural
// via grid_bar's __syncthreads vmcnt(0) drain); W2/W3 DMA-staged to LDS at
// t=0 behind a sched_barrier pin; lgkm-only phase-1 barriers.

#define RATE_F 0.001f
#define AS1 __attribute__((address_space(1)))
#define AS3 __attribute__((address_space(3)))

#define NBLK 128
#define TPB  512
#define NLEAF 8
#define PER_LEAF (NBLK / NLEAF)          // 16 arrivals per leaf per launch

// Barrier counters in module .data: zeroed at load, never re-poisoned.
// Each counter on its own 128B cacheline. [barrier][leaf]
__device__ unsigned g_leaf[2][NLEAF][32] = {};
__device__ unsigned g_root[2][32] = {};

__device__ __forceinline__ void gl_lds16(const float* g, float* l)
{
    // one instruction: 64 lanes x 16B -> LDS[l .. l+1024), l wave-uniform
    __builtin_amdgcn_global_load_lds((const AS1 void*)g, (AS3 void*)l, 16, 0, 0);
}

// Raw workgroup barrier: waits LDS/SMEM (lgkmcnt) only, NOT vmcnt -- keeps
// the W2/W3 DMA in flight across phase-1 syncs.
__device__ __forceinline__ void lgkm_barrier()
{
    asm volatile("s_waitcnt lgkmcnt(0)" ::: "memory");
    __builtin_amdgcn_s_barrier();
    __builtin_amdgcn_sched_barrier(0);
}

// coherent staging (phases 2/3): agent-scope loads bypass stale L1/L2,
// fetch from IF (the coherence point). 8B granules: 8 issues/thread.
__device__ __forceinline__ void stage_v_coh(const float* __restrict__ vin,
                                            float* __restrict__ vsh, int tid)
{
    const unsigned long long* p = (const unsigned long long*)vin; // 4096 qwords
    unsigned long long* q = (unsigned long long*)vsh;
    #pragma unroll
    for (int k = 0; k < 8; k++) {
        const int i = tid + k * TPB;            // wave-coalesced qwords
        q[i] = __hip_atomic_load(p + i, __ATOMIC_RELAXED,
                                 __HIP_MEMORY_SCOPE_AGENT);
    }
}

// wave b (of 8) reduces batch b: 64 lanes x 4 float4 = 1024 floats.
__device__ __forceinline__ void batch_sums(const float* __restrict__ vsh,
                                           float* __restrict__ svs,
                                           float* __restrict__ s2s, int tid)
{
    const int b = tid >> 6, j = tid & 63;       // wave index == batch index
    float sv = 0.f, s2 = 0.f;
    #pragma unroll
    for (int k = 0; k < 4; k++) {
        const float4 v = *(const float4*)&vsh[b * 1024 + (j + k * 64) * 4];
        sv += v.x + v.y + v.z + v.w;
        s2 += v.x * v.x + v.y * v.y + v.z * v.z + v.w * v.w;
    }
    #pragma unroll
    for (int m = 32; m >= 1; m >>= 1) {         // full 64-lane butterfly
        sv += __shfl_xor(sv, m, 64);
        s2 += __shfl_xor(s2, m, 64);
    }
    if (j == 0) { svs[b] = sv; s2s[b] = s2; }
}

__device__ __forceinline__ void epilogue(
    float acc[8], float bias_o, const float* __restrict__ svs,
    const float* __restrict__ s2s,
    float a0, float a1, float a2, float cc, float rr,
    float* __restrict__ vout, int o, int n_out, int lane, bool coh_store)
{
    #pragma unroll
    for (int b = 0; b < 8; b++) {
        #pragma unroll
        for (int m = 32; m >= 1; m >>= 1)
            acc[b] += __shfl_xor(acc[b], m, 64);
    }
    if (lane < 8) {
        const int b = lane;
        const float dot = acc[b];
        float vj = dot + bias_o;
        vj = vj > 0.f ? vj : 0.f;
        const float outv = vj + rr * (a0 * s2s[b] + a1 * dot
                                      + (a2 * vj + cc) * svs[b]);
        float* dst = vout + (size_t)b * n_out + o;
        if (coh_store)
            __hip_atomic_store(dst, outv, __ATOMIC_RELAXED,
                               __HIP_MEMORY_SCOPE_AGENT);
        else
            *dst = outv;
    }
}

__device__ __forceinline__ void layer_reg(
    const float4 wr[4], float bias_o, const float* __restrict__ vsh,
    const float* __restrict__ svs, const float* __restrict__ s2s,
    float a0, float a1, float a2, float cc, float rr,
    float* __restrict__ vout, int o, int n_out, int lane, bool coh_store)
{
    float acc[8] = {0.f, 0.f, 0.f, 0.f, 0.f, 0.f, 0.f, 0.f};
    #pragma unroll
    for (int u = 0; u < 4; u++) {
        const float4 wv = wr[u];
        #pragma unroll
        for (int b = 0; b < 8; b++) {
            const float4 v = *(const float4*)&vsh[b * 1024 + (u * 64 + lane) * 4];
            acc[b] += wv.x * v.x + wv.y * v.y + wv.z * v.z + wv.w * v.w;
        }
    }
    epilogue(acc, bias_o, svs, s2s, a0, a1, a2, cc, rr,
             vout, o, n_out, lane, coh_store);
}

__device__ __forceinline__ void layer_lds(
    const float* __restrict__ wlds, float bias_o, const float* __restrict__ vsh,
    const float* __restrict__ svs, const float* __restrict__ s2s,
    float a0, float a1, float a2, float cc, float rr,
    float* __restrict__ vout, int o, int n_out, int lane, bool coh_store)
{
    float acc[8] = {0.f, 0.f, 0.f, 0.f, 0.f, 0.f, 0.f, 0.f};
    #pragma unroll
    for (int u = 0; u < 4; u++) {
        const float4 wv = *(const float4*)&wlds[(u * 64 + lane) * 4];
        #pragma unroll
        for (int b = 0; b < 8; b++) {
            const float4 v = *(const float4*)&vsh[b * 1024 + (u * 64 + lane) * 4];
            acc[b] += wv.x * v.x + wv.y * v.y + wv.z * v.z + wv.w * v.w;
        }
    }
    epilogue(acc, bias_o, svs, s2s, a0, a1, a2, cc, rr,
             vout, o, n_out, lane, coh_store);
}

// Reset-free pure-relaxed TREE barrier (no wbl2/inv, no initialization).
// Leaf = blk&7 (own cacheline): 16 arrivals/launch, 8 leaves drain in
// parallel. 16th arriver on a leaf adds 1 to the root; spinners poll only
// the root (8 adds/launch). Launch index n = leaf_ticket/PER_LEAF; wait
// for root >= (n+1)*NLEAF, wrap-safe. Launches stream-serialize, so
// tickets of one launch span exactly [n*PER_LEAF,(n+1)*PER_LEAF) per leaf.
// Leading __syncthreads supplies the vmcnt(0) drain that orders this
// block's agent-scope v-stores (and the weight DMA) before arrival.
__device__ __forceinline__ void grid_bar(unsigned* leaf, unsigned* root)
{
    __syncthreads();   // s_waitcnt vmcnt(0): block's sc0|sc1 stores COMPLETE
    if (threadIdx.x == 0) {
        const unsigned t =
            __hip_atomic_fetch_add(leaf, 1u, __ATOMIC_RELAXED,
                                   __HIP_MEMORY_SCOPE_AGENT);
        const unsigned n = t / PER_LEAF;               // launch index
        if ((t & (PER_LEAF - 1u)) == PER_LEAF - 1u)    // last on this leaf
            __hip_atomic_fetch_add(root, 1u, __ATOMIC_RELAXED,
                                   __HIP_MEMORY_SCOPE_AGENT);
        const unsigned target = (n + 1u) * NLEAF;
        while ((int)(__hip_atomic_load(root, __ATOMIC_RELAXED,
                                       __HIP_MEMORY_SCOPE_AGENT) - target) < 0)
            __builtin_amdgcn_s_sleep(1);
    }
    __syncthreads();
}

__global__ __launch_bounds__(TPB) void hebb_fused(
    const float* __restrict__ x,
    const float* __restrict__ W1, const float* __restrict__ b1,
    const float* __restrict__ W2, const float* __restrict__ b2,
    const float* __restrict__ W3, const float* __restrict__ b3,
    const float* __restrict__ cw1, const float* __restrict__ cb1,
    const float* __restrict__ cw2, const float* __restrict__ cb2,
    const int* __restrict__ batch_num,
    float* __restrict__ v1, float* __restrict__ v2, float* __restrict__ out)
{
    __shared__ __align__(16) float vsh[8 * 1024];   // 32 KB activations
    __shared__ __align__(16) float w2sh[8 * 1024];  // 32 KB: W2 rows, 1/wave
    __shared__ __align__(16) float w3sh[4 * 1024];  // 16 KB: W3 rows (w 0..3)
    __shared__ float svs[8], s2s[8];

    const int tid  = threadIdx.x;
    const int w    = tid >> 6, lane = tid & 63;
    const int blk  = blockIdx.x;
    const int leaf = blk & (NLEAF - 1);
    const int o12  = blk * 8 + w;            // layer 1/2 row (0..1023)
    const int o3   = blk * 4 + (w & 3);      // layer 3 row
    const bool act3 = (w < 4);

    // ---- (1) x -> regs (oldest vmem ops: counted waits see only these) ----
    float4 xr[4];
    {
        const float4* xp = (const float4*)x;
        #pragma unroll
        for (int k = 0; k < 4; k++) xr[k] = xp[tid + k * TPB];
    }
    // ---- (2) W1 row -> regs ----
    float4 w1r[4];
    {
        const float4* r1 = (const float4*)(W1 + (size_t)o12 * 1024);
        #pragma unroll
        for (int u = 0; u < 4; u++) w1r[u] = r1[u * 64 + lane];
    }
    // ---- (3) biases ----
    const float bias1 = b1[o12];
    const float bias2 = b2[o12];
    const float bias3 = act3 ? b3[o3] : 0.f;
    // ---- (4) coefficients: wave-uniform, per-thread from SMEM ----
    float a0 = 0.f, a1 = 0.f, a2 = 0.f, cc = 0.f;
    #pragma unroll
    for (int h = 0; h < 8; h++) {
        const float w2c = cw2[h];
        a0 += w2c * cw1[h * 3 + 0];
        a1 += w2c * cw1[h * 3 + 1];
        a2 += w2c * cw1[h * 3 + 2];
        cc += w2c * cb1[h];
    }
    cc += cb2[0];
    const float rr = RATE_F / (float)batch_num[0];

    // pin: everything above ISSUES before the DMA below
    __builtin_amdgcn_sched_barrier(0);

    // ---- (5) DMA-stage W2/W3 rows into LDS; stays in flight through all
    // phase-1 lgkm-only barriers, drained first at grid_bar ----
    {
        const float* g2 = W2 + (size_t)o12 * 1024 + lane * 4;
        float* l2 = w2sh + w * 1024;                 // wave-uniform dest
        #pragma unroll
        for (int c = 0; c < 4; c++) gl_lds16(g2 + c * 256, l2 + c * 256);
        if (w >= 4) {                                // waves 4..7 stage W3 rows
            const int rdx = w - 4;
            const float* g3 = W3 + (size_t)(blk * 4 + rdx) * 1024 + lane * 4;
            float* l3 = w3sh + rdx * 1024;
            #pragma unroll
            for (int c = 0; c < 4; c++) gl_lds16(g3 + c * 256, l3 + c * 256);
        }
    }

    // ---- (6) x -> LDS (counted vmcnt wait covers only xr) ----
    {
        float4* q = (float4*)vsh;
        #pragma unroll
        for (int k = 0; k < 4; k++) q[tid + k * TPB] = xr[k];
    }

    lgkm_barrier();                      // LDS visibility only; DMA untouched
    batch_sums(vsh, svs, s2s, tid);
    lgkm_barrier();
    layer_reg(w1r, bias1, vsh, svs, s2s, a0, a1, a2, cc, rr,
              v1, o12, 1024, lane, true);

    grid_bar(&g_leaf[0][leaf][0], &g_root[0][0]);

    stage_v_coh(v1, vsh, tid);
    __syncthreads();
    batch_sums(vsh, svs, s2s, tid);
    __syncthreads();
    layer_lds(w2sh + w * 1024, bias2, vsh, svs, s2s, a0, a1, a2, cc, rr,
              v2, o12, 1024, lane, true);

    grid_bar(&g_leaf[1][leaf][0], &g_root[1][0]);

    stage_v_coh(v2, vsh, tid);
    __syncthreads();
    batch_sums(vsh, svs, s2s, tid);
    __syncthreads();
    if (act3)
        layer_lds(w3sh + (w & 3) * 1024, bias3, vsh, svs, s2s,
                  a0, a1, a2, cc, rr, out, o3, 512, lane, false);
}

extern "C" void kernel_launch(void* const* d_in, const int* in_sizes, int n_in,
                              void* d_out, int out_size, void* d_ws, size_t ws_size,
                              hipStream_t stream) {
    const float* x   = (const float*)d_in[0];
    const float* W1  = (const float*)d_in[1];
    const float* b1  = (const float*)d_in[2];
    const float* W2  = (const float*)d_in[3];
    const float* b2  = (const float*)d_in[4];
    const float* W3  = (const float*)d_in[5];
    const float* b3  = (const float*)d_in[6];
    const float* cw1 = (const float*)d_in[7];
    const float* cb1 = (const float*)d_in[8];
    const float* cw2 = (const float*)d_in[9];
    const float* cb2 = (const float*)d_in[10];
    const int*   bn  = (const int*)d_in[11];

    float* v1  = (float*)d_ws;            // 8x1024 fp32 intermediate
    float* v2  = v1 + 8 * 1024;           // 8x1024 fp32 intermediate
    float* out = (float*)d_out;

    hebb_fused<<<NBLK, TPB, 0, stream>>>(x, W1, b1, W2, b2, W3, b3,
                                         cw1, cb1, cw2, cb2, bn,
                                         v1, v2, out);
}